// Round 1
// baseline (368.205 us; speedup 1.0000x reference)
//
#include <hip/hip_runtime.h>

#define IN_F   4096
#define OUT_F  11008
#define BATCH  16
#define TK     512           // K-tile staged in LDS
#define CO     16            // output channels per block (4 waves x 4 rows)
#define BLOCK  256

// Each block: 16 output channels, full K. Wave ty owns rows o0..o0+3.
// Lane tx covers k = {tx*4 .. tx*4+3} + 256*it within each 512-wide tile.
// acc[4][16]: 4 rows x 16 batches per lane; folded wave-reduction at the end.
__global__ __launch_bounds__(BLOCK, 4) void qlin_kernel(
    const float* __restrict__ x,      // [16, 4096]
    const int*   __restrict__ w,      // [11008, 4096] int8 values in int32
    const float* __restrict__ scale,  // [11008]
    const float* __restrict__ bias,   // [11008]
    float* __restrict__ out)          // [16, 11008]
{
    __shared__ float xs[BATCH][TK];   // 32 KB

    const int tid = threadIdx.x;
    const int tx  = tid & 63;
    const int ty  = tid >> 6;
    const int o0  = blockIdx.x * CO + ty * 4;

    const int4* __restrict__ wr0 = (const int4*)(w + (size_t)(o0 + 0) * IN_F);
    const int4* __restrict__ wr1 = (const int4*)(w + (size_t)(o0 + 1) * IN_F);
    const int4* __restrict__ wr2 = (const int4*)(w + (size_t)(o0 + 2) * IN_F);
    const int4* __restrict__ wr3 = (const int4*)(w + (size_t)(o0 + 3) * IN_F);

    float acc[4][16];
    #pragma unroll
    for (int r = 0; r < 4; ++r)
        #pragma unroll
        for (int b = 0; b < 16; ++b) acc[r][b] = 0.f;

    const float4* __restrict__ xg = (const float4*)x;  // row = 1024 float4

    for (int k0 = 0; k0 < IN_F; k0 += TK) {
        // ---- stage x tile [16][TK] into LDS: 2048 float4, 8 per thread ----
        #pragma unroll
        for (int j = 0; j < (BATCH * TK / 4) / BLOCK; ++j) {
            int f  = tid + j * BLOCK;        // float4 index within tile
            int b  = f >> 7;                 // / (TK/4=128)
            int kc = f & 127;
            float4 v = xg[(size_t)b * (IN_F / 4) + (k0 >> 2) + kc];
            *(float4*)&xs[b][kc * 4] = v;
        }
        __syncthreads();

        #pragma unroll
        for (int it = 0; it < TK / 256; ++it) {
            const int kl  = it * 256 + tx * 4;          // local k (x4 aligned)
            const int kg4 = (k0 >> 2) + it * 64 + tx;   // int4 index in w row

            int4 w0 = wr0[kg4];
            int4 w1 = wr1[kg4];
            int4 w2 = wr2[kg4];
            int4 w3 = wr3[kg4];

            // convert once; drop int regs
            float wf[4][4];
            wf[0][0] = (float)w0.x; wf[0][1] = (float)w0.y; wf[0][2] = (float)w0.z; wf[0][3] = (float)w0.w;
            wf[1][0] = (float)w1.x; wf[1][1] = (float)w1.y; wf[1][2] = (float)w1.z; wf[1][3] = (float)w1.w;
            wf[2][0] = (float)w2.x; wf[2][1] = (float)w2.y; wf[2][2] = (float)w2.z; wf[2][3] = (float)w2.w;
            wf[3][0] = (float)w3.x; wf[3][1] = (float)w3.y; wf[3][2] = (float)w3.z; wf[3][3] = (float)w3.w;

            // batches in chunks of 4 to bound live float4 registers
            #pragma unroll
            for (int bc = 0; bc < 4; ++bc) {
                float4 xv[4];
                #pragma unroll
                for (int bb = 0; bb < 4; ++bb)
                    xv[bb] = *(const float4*)&xs[bc * 4 + bb][kl];

                #pragma unroll
                for (int r = 0; r < 4; ++r)
                    #pragma unroll
                    for (int bb = 0; bb < 4; ++bb) {
                        acc[r][bc * 4 + bb] += wf[r][0] * xv[bb].x;
                        acc[r][bc * 4 + bb] += wf[r][1] * xv[bb].y;
                        acc[r][bc * 4 + bb] += wf[r][2] * xv[bb].z;
                        acc[r][bc * 4 + bb] += wf[r][3] * xv[bb].w;
                    }
            }
        }
        __syncthreads();
    }

    // ---- folding butterfly reduction across 64 lanes ----
    // v[i] holds partial for output i = r*16+b; after folding with halving,
    // lane tx ends holding the full sum for output index tx.
    float v[64];
    #pragma unroll
    for (int r = 0; r < 4; ++r)
        #pragma unroll
        for (int b = 0; b < 16; ++b) v[r * 16 + b] = acc[r][b];

    #pragma unroll
    for (int wd = 32; wd >= 1; wd >>= 1) {
        const bool upper = (tx & wd) != 0;
        #pragma unroll
        for (int i = 0; i < wd; ++i) {
            float lo = v[i]      + __shfl_xor(v[i],      wd);
            float hi = v[i + wd] + __shfl_xor(v[i + wd], wd);
            v[i] = upper ? hi : lo;
        }
    }

    const int r_out = tx >> 4;
    const int b_out = tx & 15;
    const int o     = o0 + r_out;
    out[(size_t)b_out * OUT_F + o] = v[0] * scale[o] + bias[o];
}

extern "C" void kernel_launch(void* const* d_in, const int* in_sizes, int n_in,
                              void* d_out, int out_size, void* d_ws, size_t ws_size,
                              hipStream_t stream) {
    const float* x     = (const float*)d_in[0];
    const int*   w     = (const int*)d_in[1];
    const float* scale = (const float*)d_in[2];
    const float* bias  = (const float*)d_in[3];
    float* out = (float*)d_out;

    dim3 grid(OUT_F / CO);   // 688 blocks
    dim3 block(BLOCK);
    qlin_kernel<<<grid, block, 0, stream>>>(x, w, scale, bias, out);
}

// Round 2
// 267.245 us; speedup vs baseline: 1.3778x; 1.3778x over previous
//
#include <hip/hip_runtime.h>

#define IN_F   4096
#define OUT_F  11008
#define BATCH  16
#define TK     512           // K-tile staged in LDS
#define CO     16            // output channels per block (4 waves x 4 rows)
#define BLOCK  256

// Each block: 16 output channels, full K. Wave ty owns rows o0..o0+3.
// Lane tx covers k = {tx*4 .. tx*4+3} + 256*it within each 512-wide tile.
// acc[64]: (row r, batch b) at index r*16+b; in-place folded wave-reduction.
// NOTE: no min-waves arg on launch_bounds — (256,4) capped VGPRs at 64 and
// spilled the whole accumulator array (230 MB scratch writes, 188 us).
__global__ __launch_bounds__(BLOCK) void qlin_kernel(
    const float* __restrict__ x,      // [16, 4096]
    const int*   __restrict__ w,      // [11008, 4096] int8 values in int32
    const float* __restrict__ scale,  // [11008]
    const float* __restrict__ bias,   // [11008]
    float* __restrict__ out)          // [16, 11008]
{
    __shared__ float xs[BATCH][TK];   // 32 KB

    const int tid = threadIdx.x;
    const int tx  = tid & 63;
    const int ty  = tid >> 6;
    const int o0  = blockIdx.x * CO + ty * 4;

    // base int4 pointer for row o0; rows are consecutive, stride IN_F/4 int4
    const int4* __restrict__ wbase = (const int4*)(w + (size_t)o0 * IN_F);

    float acc[64];
    #pragma unroll
    for (int i = 0; i < 64; ++i) acc[i] = 0.f;

    const float4* __restrict__ xg = (const float4*)x;  // row = 1024 float4

    for (int k0 = 0; k0 < IN_F; k0 += TK) {
        // ---- stage x tile [16][TK] into LDS: 2048 float4, 8 per thread ----
        #pragma unroll
        for (int j = 0; j < (BATCH * TK / 4) / BLOCK; ++j) {
            int f  = tid + j * BLOCK;        // float4 index within tile
            int b  = f >> 7;                 // / (TK/4=128)
            int kc = f & 127;
            float4 v = xg[(size_t)b * (IN_F / 4) + (k0 >> 2) + kc];
            *(float4*)&xs[b][kc * 4] = v;
        }
        __syncthreads();

        #pragma unroll
        for (int it = 0; it < TK / 256; ++it) {
            const int kl  = it * 256 + tx * 4;          // local k (x4 aligned)
            const int kg4 = (k0 >> 2) + it * 64 + tx;   // int4 index in w row

            int4 w0 = wbase[kg4];
            int4 w1 = wbase[kg4 + 1 * (IN_F / 4)];
            int4 w2 = wbase[kg4 + 2 * (IN_F / 4)];
            int4 w3 = wbase[kg4 + 3 * (IN_F / 4)];

            // convert once; int regs die here
            float wf[4][4];
            wf[0][0] = (float)w0.x; wf[0][1] = (float)w0.y; wf[0][2] = (float)w0.z; wf[0][3] = (float)w0.w;
            wf[1][0] = (float)w1.x; wf[1][1] = (float)w1.y; wf[1][2] = (float)w1.z; wf[1][3] = (float)w1.w;
            wf[2][0] = (float)w2.x; wf[2][1] = (float)w2.y; wf[2][2] = (float)w2.z; wf[2][3] = (float)w2.w;
            wf[3][0] = (float)w3.x; wf[3][1] = (float)w3.y; wf[3][2] = (float)w3.z; wf[3][3] = (float)w3.w;

            // batches in chunks of 4 to bound live float4 registers
            #pragma unroll
            for (int bc = 0; bc < 4; ++bc) {
                float4 xv[4];
                #pragma unroll
                for (int bb = 0; bb < 4; ++bb)
                    xv[bb] = *(const float4*)&xs[bc * 4 + bb][kl];

                #pragma unroll
                for (int r = 0; r < 4; ++r)
                    #pragma unroll
                    for (int bb = 0; bb < 4; ++bb) {
                        float a = acc[r * 16 + bc * 4 + bb];
                        a += wf[r][0] * xv[bb].x;
                        a += wf[r][1] * xv[bb].y;
                        a += wf[r][2] * xv[bb].z;
                        a += wf[r][3] * xv[bb].w;
                        acc[r * 16 + bc * 4 + bb] = a;
                    }
            }
        }
        __syncthreads();
    }

    // ---- in-place folding butterfly reduction across 64 lanes ----
    // After folding, lane tx holds the full sum for flat index tx = r*16+b.
    #pragma unroll
    for (int wd = 32; wd >= 1; wd >>= 1) {
        const bool upper = (tx & wd) != 0;
        #pragma unroll
        for (int i = 0; i < wd; ++i) {
            float lo = acc[i]      + __shfl_xor(acc[i],      wd);
            float hi = acc[i + wd] + __shfl_xor(acc[i + wd], wd);
            acc[i] = upper ? hi : lo;
        }
    }

    const int r_out = tx >> 4;
    const int b_out = tx & 15;
    const int o     = o0 + r_out;
    out[(size_t)b_out * OUT_F + o] = acc[0] * scale[o] + bias[o];
}

extern "C" void kernel_launch(void* const* d_in, const int* in_sizes, int n_in,
                              void* d_out, int out_size, void* d_ws, size_t ws_size,
                              hipStream_t stream) {
    const float* x     = (const float*)d_in[0];
    const int*   w     = (const int*)d_in[1];
    const float* scale = (const float*)d_in[2];
    const float* bias  = (const float*)d_in[3];
    float* out = (float*)d_out;

    dim3 grid(OUT_F / CO);   // 688 blocks
    dim3 block(BLOCK);
    qlin_kernel<<<grid, block, 0, stream>>>(x, w, scale, bias, out);
}

// Round 3
// 259.327 us; speedup vs baseline: 1.4198x; 1.0305x over previous
//
#include <hip/hip_runtime.h>

#define IN_F   4096
#define OUT_F  11008
#define BATCH  16
#define TK     512            // K-tile staged in LDS per segment
#define CO     16             // output channels per block (4 waves x 4 rows)
#define BLOCK  256
#define SPLITK 4
#define KCHUNK (IN_F / SPLITK)   // 1024 k per block

typedef int   i32x4 __attribute__((ext_vector_type(4)));

// out[b][o] = bias[o]  (pre-init so main kernel can atomicAdd partials)
__global__ __launch_bounds__(BLOCK) void init_out_kernel(
    const float* __restrict__ bias, float* __restrict__ out)
{
    int idx = blockIdx.x * BLOCK + threadIdx.x;
    if (idx < BATCH * OUT_F) {
        int o = idx % OUT_F;
        out[idx] = bias[o];
    }
}

// Block (bx, by): 16 output channels [bx*16 .. bx*16+16), K-chunk by*1024.
// Wave ty owns rows o0..o0+3. Lane tx covers k = {tx*4..tx*4+3} + 256*it.
// acc[64]: (row r, batch b) at r*16+b; in-place folded wave butterfly, then
// one atomicAdd per lane of scale[o]*partial into bias-initialized out.
__global__ __launch_bounds__(BLOCK) void qlin_kernel(
    const float* __restrict__ x,      // [16, 4096]
    const int*   __restrict__ w,      // [11008, 4096] int8 values in int32
    const float* __restrict__ scale,  // [11008]
    float* __restrict__ out)          // [16, 11008], pre-filled with bias
{
    __shared__ float xs[BATCH][TK];   // 32 KB

    const int tid = threadIdx.x;
    const int tx  = tid & 63;
    const int ty  = tid >> 6;
    const int o0  = blockIdx.x * CO + ty * 4;
    const int kb  = blockIdx.y * KCHUNK;

    const i32x4* __restrict__ wbase = (const i32x4*)(w + (size_t)o0 * IN_F);

    float acc[64];
    #pragma unroll
    for (int i = 0; i < 64; ++i) acc[i] = 0.f;

    for (int k0 = kb; k0 < kb + KCHUNK; k0 += TK) {
        // ---- stage x tile [16][TK] via async global->LDS, 16B/lane ----
        // f = float4 slot in tile; LDS byte addr = f*16 = wave-uniform + lane*16.
        #pragma unroll
        for (int j = 0; j < (BATCH * TK / 4) / BLOCK; ++j) {
            int f  = tid + j * BLOCK;
            int b  = f >> 7;                  // / (TK/4 = 128)
            int kc = f & 127;
            const float* src = x + (size_t)b * IN_F + k0 + kc * 4;
            void* dst = (char*)&xs[0][0] + (size_t)f * 16;
            __builtin_amdgcn_global_load_lds(
                (const __attribute__((address_space(1))) void*)src,
                (__attribute__((address_space(3))) void*)dst,
                16, 0, 0);
        }
        __syncthreads();   // drains vmcnt -> LDS tile complete

        #pragma unroll
        for (int it = 0; it < TK / 256; ++it) {
            const int    kl  = it * 256 + tx * 4;               // local k
            const size_t kg4 = (size_t)((k0 >> 2) + it * 64 + tx); // i32x4 idx

            // weights: stream-once -> nontemporal, keep x resident in L2
            i32x4 w0 = __builtin_nontemporal_load(wbase + kg4);
            i32x4 w1 = __builtin_nontemporal_load(wbase + kg4 + 1 * (IN_F / 4));
            i32x4 w2 = __builtin_nontemporal_load(wbase + kg4 + 2 * (IN_F / 4));
            i32x4 w3 = __builtin_nontemporal_load(wbase + kg4 + 3 * (IN_F / 4));

            float wf[4][4];
            #pragma unroll
            for (int e = 0; e < 4; ++e) {
                wf[0][e] = (float)w0[e];
                wf[1][e] = (float)w1[e];
                wf[2][e] = (float)w2[e];
                wf[3][e] = (float)w3[e];
            }

            // batches in chunks of 4 to bound live float4 registers
            #pragma unroll
            for (int bc = 0; bc < 4; ++bc) {
                float4 xv[4];
                #pragma unroll
                for (int bb = 0; bb < 4; ++bb)
                    xv[bb] = *(const float4*)&xs[bc * 4 + bb][kl];

                #pragma unroll
                for (int r = 0; r < 4; ++r)
                    #pragma unroll
                    for (int bb = 0; bb < 4; ++bb) {
                        float a = acc[r * 16 + bc * 4 + bb];
                        a += wf[r][0] * xv[bb].x;
                        a += wf[r][1] * xv[bb].y;
                        a += wf[r][2] * xv[bb].z;
                        a += wf[r][3] * xv[bb].w;
                        acc[r * 16 + bc * 4 + bb] = a;
                    }
            }
        }
        __syncthreads();   // before next stage overwrites xs
    }

    // ---- in-place folding butterfly across 64 lanes ----
    // After folding, lane tx holds the full partial for flat index tx = r*16+b.
    #pragma unroll
    for (int wd = 32; wd >= 1; wd >>= 1) {
        const bool upper = (tx & wd) != 0;
        #pragma unroll
        for (int i = 0; i < wd; ++i) {
            float lo = acc[i]      + __shfl_xor(acc[i],      wd);
            float hi = acc[i + wd] + __shfl_xor(acc[i + wd], wd);
            acc[i] = upper ? hi : lo;
        }
    }

    const int o = o0 + (tx >> 4);
    const int b = tx & 15;
    atomicAdd(&out[(size_t)b * OUT_F + o], acc[0] * scale[o]);
}

extern "C" void kernel_launch(void* const* d_in, const int* in_sizes, int n_in,
                              void* d_out, int out_size, void* d_ws, size_t ws_size,
                              hipStream_t stream) {
    const float* x     = (const float*)d_in[0];
    const int*   w     = (const int*)d_in[1];
    const float* scale = (const float*)d_in[2];
    const float* bias  = (const float*)d_in[3];
    float* out = (float*)d_out;

    init_out_kernel<<<(BATCH * OUT_F + BLOCK - 1) / BLOCK, BLOCK, 0, stream>>>(bias, out);

    dim3 grid(OUT_F / CO, SPLITK);   // 688 x 4 = 2752 blocks
    qlin_kernel<<<grid, dim3(BLOCK), 0, stream>>>(x, w, scale, out);
}